// Round 6
// baseline (699.947 us; speedup 1.0000x reference)
//
#include <hip/hip_runtime.h>
#include <stdint.h>

// ---------------------------------------------------------------------------
// NeuroplasticSparseAttention  (B=2, T=2048, C=1024, H=16, D=64, fp32)
// Round 6: attention blocks widened to 128 q-rows / 8 waves (512 thr).
//   - 2 blocks/CU (72KB LDS) -> 16 waves/CU occupancy (was 8)
//   - K/V staging + barriers amortized over 2x compute
//   - per-wave math identical to R5 (bit-identical absmax expected)
// GEMM/conv pipeline unchanged from R5 (validated).
// ---------------------------------------------------------------------------

typedef _Float16 half8 __attribute__((ext_vector_type(8)));
typedef _Float16 half4 __attribute__((ext_vector_type(4)));
typedef float f32x4 __attribute__((ext_vector_type(4)));

#define MFMA16(a, b, c) __builtin_amdgcn_mfma_f32_16x16x32_f16(a, b, c, 0, 0, 0)

__device__ __forceinline__ void gld16(const void* g, void* l) {
  __builtin_amdgcn_global_load_lds(
      (const __attribute__((address_space(1))) void*)g,
      (__attribute__((address_space(3))) void*)l, 16, 0, 0);
}

__device__ __forceinline__ uint32_t rotl32(uint32_t x, uint32_t d) {
  return (x << d) | (x >> (32u - d));
}

// threefry2x32-20, key=(0,42), partitionable, out = x0^x1  (verified R1/R4/R5)
__device__ __forceinline__ bool regrow(uint32_t b, uint32_t hts) {
  const uint32_t ks1 = 42u;
  const uint32_t ks2 = 0x1BD11BDAu ^ 42u;
  uint32_t x0 = 0u;
  uint32_t x1 = b * 0x4000000u + hts;
  x1 += ks1;
#define TF_R(r) { x0 += x1; x1 = rotl32(x1, r); x1 ^= x0; }
  TF_R(13) TF_R(15) TF_R(26) TF_R(6)  x0 += ks1; x1 += ks2 + 1u;
  TF_R(17) TF_R(29) TF_R(16) TF_R(24) x0 += ks2; x1 += 0u  + 2u;
  TF_R(13) TF_R(15) TF_R(26) TF_R(6)  x0 += 0u;  x1 += ks1 + 3u;
  TF_R(17) TF_R(29) TF_R(16) TF_R(24) x0 += ks1; x1 += ks2 + 4u;
  TF_R(13) TF_R(15) TF_R(26) TF_R(6)  x0 += ks2; x1 += 0u  + 5u;
#undef TF_R
  uint32_t r32 = x0 ^ x1;
  float f = __uint_as_float((r32 >> 9) | 0x3f800000u) - 1.0f;
  return f < 0.05f;
}

// ---------------------------------------------------------------------------
// conv_x: x [4096][1024] f32 -> xh/xl swizzled f16. 1 thread = 8 elems.
// ---------------------------------------------------------------------------
__global__ __launch_bounds__(256) void conv_x(const float* __restrict__ x,
                                              _Float16* __restrict__ xh,
                                              _Float16* __restrict__ xl) {
  int idx = blockIdx.x * 256 + threadIdx.x;
  int row = idx >> 7;
  int c8 = (idx & 127) << 3;
  const float* s = x + (size_t)row * 1024 + c8;
  float4 v0 = *(const float4*)s;
  float4 v1 = *(const float4*)(s + 4);
  float vv[8] = {v0.x, v0.y, v0.z, v0.w, v1.x, v1.y, v1.z, v1.w};
  half8 hh, ll;
#pragma unroll
  for (int i = 0; i < 8; ++i) {
    hh[i] = (_Float16)vv[i];
    ll[i] = (_Float16)(vv[i] - (float)hh[i]);
  }
  size_t o = (size_t)row * 1024 + (c8 ^ ((row & 7) << 3));
  *(half8*)&xh[o] = hh;
  *(half8*)&xl[o] = ll;
}

// ---------------------------------------------------------------------------
// conv_w: W [1024][N] f32 -> Wth/Wtl [N][1024] f16 transposed + swizzled.
// ---------------------------------------------------------------------------
__global__ __launch_bounds__(256) void conv_w(const float* __restrict__ W, int N,
                                              _Float16* __restrict__ Wth,
                                              _Float16* __restrict__ Wtl) {
  __shared__ float sW[64][68];
  const int n0 = blockIdx.x * 64, k0 = blockIdx.y * 64;
  const int t = threadIdx.x;
  const int kr = t >> 2, nc = (t & 3) * 16;
#pragma unroll
  for (int j = 0; j < 4; ++j)
    *(float4*)&sW[kr][nc + 4 * j] =
        *(const float4*)&W[(size_t)(k0 + kr) * N + n0 + nc + 4 * j];
  __syncthreads();
  const int nl = t >> 2, ks = (t & 3) * 16;
#pragma unroll
  for (int j = 0; j < 2; ++j) {
    int k8 = ks + j * 8;
    half8 hh, ll;
#pragma unroll
    for (int e = 0; e < 8; ++e) {
      float v = sW[k8 + e][nl];
      hh[e] = (_Float16)v;
      ll[e] = (_Float16)(v - (float)hh[e]);
    }
    size_t o = (size_t)(n0 + nl) * 1024 + ((k0 + k8) ^ (((n0 + nl) & 7) << 3));
    *(half8*)&Wth[o] = hh;
    *(half8*)&Wtl[o] = ll;
  }
}

// ---------------------------------------------------------------------------
// f16x3 GEMM (unchanged from R5, validated).
// ---------------------------------------------------------------------------
template <int PRE>
__global__ __launch_bounds__(256) void gemm_f16x3(
    const _Float16* __restrict__ Ah, const _Float16* __restrict__ Al,
    const float* __restrict__ Afp,
    const _Float16* __restrict__ Bth, const _Float16* __restrict__ Btl,
    const float* __restrict__ bias, int N, int outMode,
    _Float16* __restrict__ Qh, _Float16* __restrict__ Ql,
    _Float16* __restrict__ Kh, _Float16* __restrict__ Kl,
    _Float16* __restrict__ Vt, float* __restrict__ out)
{
  __shared__ _Float16 sAh[8192], sAl[8192], sBh[8192], sBl[8192];
  const int tid = threadIdx.x;
  const int wv = tid >> 6, lane = tid & 63;
  const int lg = lane >> 4, m15 = lane & 15;
  const int wr = wv >> 1, wc = wv & 1;
  const int m0 = blockIdx.y << 7, n0 = blockIdx.x << 7;
  const int srow = lane >> 3;
  const int schk = (lane & 7) << 3;

  f32x4 acc[4][4];
#pragma unroll
  for (int i = 0; i < 4; ++i)
#pragma unroll
    for (int j = 0; j < 4; ++j) acc[i][j] = (f32x4){0.f, 0.f, 0.f, 0.f};

  for (int g = 0; g < 16; ++g) {
    __syncthreads();
#pragma unroll
    for (int i = 0; i < 4; ++i) {
      int rb = (wv << 5) + (i << 3);
      size_t so = (size_t)(n0 + rb + srow) * 1024 + (g << 6) + schk;
      gld16(Bth + so, &sBh[rb << 6]);
      gld16(Btl + so, &sBl[rb << 6]);
    }
    if (PRE) {
#pragma unroll
      for (int i = 0; i < 4; ++i) {
        int rb = (wv << 5) + (i << 3);
        size_t so = (size_t)(m0 + rb + srow) * 1024 + (g << 6) + schk;
        gld16(Ah + so, &sAh[rb << 6]);
        gld16(Al + so, &sAl[rb << 6]);
      }
    } else {
      int r = tid >> 1, c0 = (tid & 1) << 5;
      const float* src = Afp + (size_t)(m0 + r) * 1024 + (g << 6) + c0;
#pragma unroll
      for (int i = 0; i < 8; ++i) {
        float4 v = *(const float4*)(src + (i << 2));
        half4 hh = {(_Float16)v.x, (_Float16)v.y, (_Float16)v.z, (_Float16)v.w};
        half4 ll = {(_Float16)(v.x - (float)hh[0]), (_Float16)(v.y - (float)hh[1]),
                    (_Float16)(v.z - (float)hh[2]), (_Float16)(v.w - (float)hh[3])};
        int off = (r << 6) + ((c0 + (i << 2)) ^ ((r & 7) << 3));
        *(half4*)&sAh[off] = hh;
        *(half4*)&sAl[off] = ll;
      }
    }
    __syncthreads();

#pragma unroll
    for (int ks = 0; ks < 2; ++ks) {
      half8 ah[4], al[4], bh[4], bl[4];
#pragma unroll
      for (int mi = 0; mi < 4; ++mi) {
        int row = (wr << 6) + (mi << 4) + m15;
        int off = (row << 6) + (((ks << 5) + (lg << 3)) ^ ((row & 7) << 3));
        ah[mi] = *(const half8*)&sAh[off];
        al[mi] = *(const half8*)&sAl[off];
      }
#pragma unroll
      for (int nj = 0; nj < 4; ++nj) {
        int row = (wc << 6) + (nj << 4) + m15;
        int off = (row << 6) + (((ks << 5) + (lg << 3)) ^ ((row & 7) << 3));
        bh[nj] = *(const half8*)&sBh[off];
        bl[nj] = *(const half8*)&sBl[off];
      }
#pragma unroll
      for (int mi = 0; mi < 4; ++mi)
#pragma unroll
        for (int nj = 0; nj < 4; ++nj) {
          acc[mi][nj] = MFMA16(ah[mi], bh[nj], acc[mi][nj]);
          acc[mi][nj] = MFMA16(ah[mi], bl[nj], acc[mi][nj]);
          acc[mi][nj] = MFMA16(al[mi], bh[nj], acc[mi][nj]);
        }
    }
  }

#pragma unroll
  for (int nj = 0; nj < 4; ++nj) {
    int n = n0 + (wc << 6) + (nj << 4) + m15;
    float bv = bias[n];
    int which = n >> 10;
    int hh_ = (n & 1023) >> 6;
    int d = n & 63;
#pragma unroll
    for (int mi = 0; mi < 4; ++mi) {
#pragma unroll
      for (int r = 0; r < 4; ++r) {
        int m = m0 + (wr << 6) + (mi << 4) + (lg << 2) + r;
        float v = acc[mi][nj][r] + bv;
        if (outMode == 1) {
          out[(size_t)m * N + n] = v;
        } else {
          _Float16 hi = (_Float16)v;
          _Float16 lo = (_Float16)(v - (float)hi);
          int b = m >> 11, t = m & 2047;
          if (which == 2) {
            size_t o = ((size_t)((b << 4) + hh_) * 64 + d) * 2048
                     + (t ^ ((d & 7) << 3));
            Vt[o] = hi;
          } else {
            size_t o = ((size_t)((b << 4) + hh_) * 2048 + t) * 64
                     + (d ^ ((t & 7) << 3));
            if (which == 0) { Qh[o] = hi; Ql[o] = lo; }
            else            { Kh[o] = hi; Kl[o] = lo; }
          }
        }
      }
    }
  }
}

// ---------------------------------------------------------------------------
// MFMA attention, 128 q-rows / 8 waves per block. Wave w owns q-rows
// [w*16, +16) of the tile; per-wave math identical to R5.
// LDS 72KB -> 2 blocks/CU (16 waves/CU).
// ---------------------------------------------------------------------------
__global__ __launch_bounds__(512) void attn_mfma(
    const _Float16* __restrict__ Qhg, const _Float16* __restrict__ Qlg,
    const _Float16* __restrict__ Khg, const _Float16* __restrict__ Klg,
    const _Float16* __restrict__ Vtg,
    _Float16* __restrict__ AOh, _Float16* __restrict__ AOl)
{
  __shared__ _Float16 sQh[8192], sQl[8192];   // [128][64] swizzled
  __shared__ _Float16 sKh[4096], sKl[4096];   // [64][64]
  __shared__ _Float16 sVt[4096];              // [64 d][64 s]
  __shared__ _Float16 sP[8192];               // [128][64]

  const int tid = threadIdx.x;
  const int wv = tid >> 6, lane = tid & 63;
  const int lg = lane >> 4, m15 = lane & 15;
  const int h = blockIdx.y, b = blockIdx.z;
  const size_t bh = (size_t)(b * 16 + h);
  const _Float16* Qhb = Qhg + bh * 2048 * 64;
  const _Float16* Qlb = Qlg + bh * 2048 * 64;
  const _Float16* Khb = Khg + bh * 2048 * 64;
  const _Float16* Klb = Klg + bh * 2048 * 64;
  const _Float16* Vtb = Vtg + bh * 64 * 2048;

  const int srow = lane >> 3, schk = (lane & 7) << 3;
  const int w16 = wv << 4;                  // q-row base within tile
  const int w8 = wv << 3;                   // K/V staging row base

  const int qt = 15 - (int)blockIdx.x;      // longest blocks dispatch first
  const int t0 = qt << 7;                   // 128-row q tile
  const int ktmax = 2 * qt + 1;

  // ---- Q staging (16 rows per wave, hi+lo) ----
  {
    size_t o0 = (size_t)(t0 + w16 + srow) * 64 + schk;
    size_t o1 = (size_t)(t0 + w16 + 8 + srow) * 64 + schk;
    gld16(Qhb + o0, &sQh[w16 << 6]);
    gld16(Qhb + o1, &sQh[(w16 + 8) << 6]);
    gld16(Qlb + o0, &sQl[w16 << 6]);
    gld16(Qlb + o1, &sQl[(w16 + 8) << 6]);
  }
  __syncthreads();

  const int qrow = w16 + m15;
  const int qsw = (qrow & 7) << 3;
  const half8 qh0 = *(const half8*)&sQh[(qrow << 6) + ((lg << 3) ^ qsw)];
  const half8 qh1 = *(const half8*)&sQh[(qrow << 6) + (((lg << 3) + 32) ^ qsw)];
  const half8 ql0 = *(const half8*)&sQl[(qrow << 6) + ((lg << 3) ^ qsw)];
  const half8 ql1 = *(const half8*)&sQl[(qrow << 6) + (((lg << 3) + 32) ^ qsw)];

  const int qg = t0 + w16 + (lg << 2);      // this lane's first q row (global)

  float m_[4], l_[4];
#pragma unroll
  for (int r = 0; r < 4; ++r) { m_[r] = -INFINITY; l_[r] = 0.0f; }

  // ---------------- pass 1: online m, l ----------------
  for (int kt = 0; kt <= ktmax; ++kt) {
    __syncthreads();
    {
      size_t o = (size_t)((kt << 6) + w8 + srow) * 64 + schk;
      gld16(Khb + o, &sKh[w8 << 6]);
      gld16(Klb + o, &sKl[w8 << 6]);
    }
    __syncthreads();

    float sc[4][4];
#pragma unroll
    for (int nt = 0; nt < 4; ++nt) {
      const int krow = (nt << 4) + m15;
      const int ksw = (krow & 7) << 3;
      half8 kh0 = *(const half8*)&sKh[(krow << 6) + ((lg << 3) ^ ksw)];
      half8 kh1 = *(const half8*)&sKh[(krow << 6) + (((lg << 3) + 32) ^ ksw)];
      half8 kl0 = *(const half8*)&sKl[(krow << 6) + ((lg << 3) ^ ksw)];
      half8 kl1 = *(const half8*)&sKl[(krow << 6) + (((lg << 3) + 32) ^ ksw)];
      f32x4 c = {0.f, 0.f, 0.f, 0.f};
      c = MFMA16(qh0, kh0, c);
      c = MFMA16(qh1, kh1, c);
      c = MFMA16(qh0, kl0, c);
      c = MFMA16(qh1, kl1, c);
      c = MFMA16(ql0, kh0, c);
      c = MFMA16(ql1, kh1, c);
      const int sg = (kt << 6) + (nt << 4) + m15;
#pragma unroll
      for (int r = 0; r < 4; ++r) {
        float s = c[r] * 0.125f;
        if (kt >= 2 * qt && sg > qg + r) s = -1e30f;
        sc[nt][r] = s;
      }
    }
#pragma unroll
    for (int r = 0; r < 4; ++r) {
      float tm = fmaxf(fmaxf(sc[0][r], sc[1][r]), fmaxf(sc[2][r], sc[3][r]));
      tm = fmaxf(tm, __shfl_xor(tm, 1));
      tm = fmaxf(tm, __shfl_xor(tm, 2));
      tm = fmaxf(tm, __shfl_xor(tm, 4));
      tm = fmaxf(tm, __shfl_xor(tm, 8));
      float mn = fmaxf(m_[r], tm);
      float ps = __expf(sc[0][r] - mn) + __expf(sc[1][r] - mn)
               + __expf(sc[2][r] - mn) + __expf(sc[3][r] - mn);
      ps += __shfl_xor(ps, 1);
      ps += __shfl_xor(ps, 2);
      ps += __shfl_xor(ps, 4);
      ps += __shfl_xor(ps, 8);
      l_[r] = l_[r] * __expf(m_[r] - mn) + ps;
      m_[r] = mn;
    }
  }

  float rl[4];
#pragma unroll
  for (int r = 0; r < 4; ++r) rl[r] = 1.0f / l_[r];

  f32x4 oacc[4];
#pragma unroll
  for (int nt = 0; nt < 4; ++nt) oacc[nt] = (f32x4){0.f, 0.f, 0.f, 0.f};

  const uint32_t hqbase = (uint32_t)(h * 2048 + qg) * 2048u;

  // ---------------- pass 2: p -> prune/regrow -> PV ----------------
  for (int kt = 0; kt <= ktmax; ++kt) {
    __syncthreads();
    {
      size_t o = (size_t)((kt << 6) + w8 + srow) * 64 + schk;
      gld16(Khb + o, &sKh[w8 << 6]);
      gld16(Klb + o, &sKl[w8 << 6]);
      size_t vo = (size_t)(w8 + srow) * 2048 + (kt << 6) + schk;
      gld16(Vtb + vo, &sVt[w8 << 6]);
    }
    __syncthreads();

    float sc[4][4];
#pragma unroll
    for (int nt = 0; nt < 4; ++nt) {
      const int krow = (nt << 4) + m15;
      const int ksw = (krow & 7) << 3;
      half8 kh0 = *(const half8*)&sKh[(krow << 6) + ((lg << 3) ^ ksw)];
      half8 kh1 = *(const half8*)&sKh[(krow << 6) + (((lg << 3) + 32) ^ ksw)];
      half8 kl0 = *(const half8*)&sKl[(krow << 6) + ((lg << 3) ^ ksw)];
      half8 kl1 = *(const half8*)&sKl[(krow << 6) + (((lg << 3) + 32) ^ ksw)];
      f32x4 c = {0.f, 0.f, 0.f, 0.f};
      c = MFMA16(qh0, kh0, c);
      c = MFMA16(qh1, kh1, c);
      c = MFMA16(qh0, kl0, c);
      c = MFMA16(qh1, kl1, c);
      c = MFMA16(ql0, kh0, c);
      c = MFMA16(ql1, kh1, c);
      const int sg = (kt << 6) + (nt << 4) + m15;
#pragma unroll
      for (int r = 0; r < 4; ++r) {
        float s = c[r] * 0.125f;
        if (kt >= 2 * qt && sg > qg + r) s = -1e30f;
        sc[nt][r] = s;
      }
    }

#pragma unroll
    for (int nt = 0; nt < 4; ++nt) {
#pragma unroll
      for (int r = 0; r < 4; ++r) {
        float pv = __expf(sc[nt][r] - m_[r]) * rl[r];
        float outp = 0.0f;
        if (pv > 0.01f) {
          outp = pv;
        } else if (pv > 0.0f) {
          uint32_t hts = hqbase + (uint32_t)r * 2048u
                       + (uint32_t)((kt << 6) + (nt << 4) + m15);
          if (regrow((uint32_t)b, hts)) outp = pv;
        }
        int q = w16 + (lg << 2) + r;
        sP[(q << 6) + (((nt << 4) + m15) ^ ((q & 7) << 3))] = (_Float16)outp;
      }
    }
    __syncthreads();

    const int prow = w16 + m15;
    const int psw = (prow & 7) << 3;
    half8 pa0 = *(const half8*)&sP[(prow << 6) + ((lg << 3) ^ psw)];
    half8 pa1 = *(const half8*)&sP[(prow << 6) + (((lg << 3) + 32) ^ psw)];
#pragma unroll
    for (int nt = 0; nt < 4; ++nt) {
      const int vrow = (nt << 4) + m15;
      const int vsw = (vrow & 7) << 3;
      half8 vb0 = *(const half8*)&sVt[(vrow << 6) + ((lg << 3) ^ vsw)];
      half8 vb1 = *(const half8*)&sVt[(vrow << 6) + (((lg << 3) + 32) ^ vsw)];
      oacc[nt] = MFMA16(pa0, vb0, oacc[nt]);
      oacc[nt] = MFMA16(pa1, vb1, oacc[nt]);
    }
  }

  // epilogue: AOh/AOl [4096][1024] swizzled by (row&7)
#pragma unroll
  for (int nt = 0; nt < 4; ++nt)
#pragma unroll
    for (int r = 0; r < 4; ++r) {
      int q = qg + r;
      int col = (h << 6) + (nt << 4) + m15;
      int mrow = (b << 11) + q;
      float v = oacc[nt][r];
      _Float16 hi = (_Float16)v;
      _Float16 lo = (_Float16)(v - (float)hi);
      size_t o = (size_t)mrow * 1024 + (col ^ ((mrow & 7) << 3));
      AOh[o] = hi;
      AOl[o] = lo;
    }
}

// ---------------------------------------------------------------------------
extern "C" void kernel_launch(void* const* d_in, const int* in_sizes, int n_in,
                              void* d_out, int out_size, void* d_ws, size_t ws_size,
                              hipStream_t stream) {
  const float* x    = (const float*)d_in[0];
  const float* Wqkv = (const float*)d_in[1];
  const float* bqkv = (const float*)d_in[2];
  const float* Wout = (const float*)d_in[3];
  const float* bout = (const float*)d_in[4];
  float* out = (float*)d_out;

  const size_t MB = 1u << 20;
  char* w = (char*)d_ws;
  _Float16* Qh = (_Float16*)(w);
  _Float16* Ql = (_Float16*)(w + 8 * MB);
  _Float16* Kh = (_Float16*)(w + 16 * MB);
  _Float16* Kl = (_Float16*)(w + 24 * MB);
  _Float16* Vt = (_Float16*)(w + 32 * MB);

  const bool pre = (ws_size >= 72 * MB);
  _Float16 *xh, *xl, *Wqh, *Wql, *Woh, *Wol, *AOh, *AOl;
  if (pre) {
    xh  = (_Float16*)(w + 40 * MB);
    xl  = (_Float16*)(w + 48 * MB);
    Wqh = (_Float16*)(w + 56 * MB);
    Wql = (_Float16*)(w + 62 * MB);
    Woh = (_Float16*)(w + 68 * MB);
    Wol = (_Float16*)(w + 70 * MB);
  } else {
    xh = xl = nullptr;
    Wqh = (_Float16*)(w + 40 * MB);
    Wql = (_Float16*)(w + 46 * MB);
    Woh = (_Float16*)(w + 56 * MB);
    Wol = (_Float16*)(w + 58 * MB);
  }
  AOh = (_Float16*)(w + 40 * MB);
  AOl = (_Float16*)(w + 48 * MB);

  dim3 blk(256);
  if (pre) conv_x<<<2048, blk, 0, stream>>>(x, xh, xl);
  conv_w<<<dim3(48, 16), blk, 0, stream>>>(Wqkv, 3072, Wqh, Wql);
  conv_w<<<dim3(16, 16), blk, 0, stream>>>(Wout, 1024, Woh, Wol);

  if (pre)
    gemm_f16x3<1><<<dim3(24, 32), blk, 0, stream>>>(
        xh, xl, nullptr, Wqh, Wql, bqkv, 3072, 0, Qh, Ql, Kh, Kl, Vt, nullptr);
  else
    gemm_f16x3<0><<<dim3(24, 32), blk, 0, stream>>>(
        nullptr, nullptr, x, Wqh, Wql, bqkv, 3072, 0, Qh, Ql, Kh, Kl, Vt, nullptr);

  attn_mfma<<<dim3(16, 16, 2), dim3(512), 0, stream>>>(Qh, Ql, Kh, Kl, Vt,
                                                       AOh, AOl);

  gemm_f16x3<1><<<dim3(8, 32), blk, 0, stream>>>(
      AOh, AOl, nullptr, Woh, Wol, bout, 1024, 1,
      nullptr, nullptr, nullptr, nullptr, nullptr, out);
}

// Round 8
// 461.940 us; speedup vs baseline: 1.5152x; 1.5152x over previous
//
#include <hip/hip_runtime.h>
#include <stdint.h>

// ---------------------------------------------------------------------------
// NeuroplasticSparseAttention  (B=2, T=2048, C=1024, H=16, D=64, fp32)
// Round 8 = Round 7 resubmit (R7 hit GPUAcquisitionTimeout; never ran).
// R5 attention shape (uniform {p,31-p} paired blocks, 4 waves, 64-row
// q-tiles) + double-buffered K/V staging with counted vmcnt
// (raw s_barrier, never vmcnt(0) mid-loop). GEMM/conv unchanged (R5-validated).
// ---------------------------------------------------------------------------

typedef _Float16 half8 __attribute__((ext_vector_type(8)));
typedef _Float16 half4 __attribute__((ext_vector_type(4)));
typedef float f32x4 __attribute__((ext_vector_type(4)));

#define MFMA16(a, b, c) __builtin_amdgcn_mfma_f32_16x16x32_f16(a, b, c, 0, 0, 0)
#define SBAR() __builtin_amdgcn_s_barrier()
#define SCHED0() __builtin_amdgcn_sched_barrier(0)

__device__ __forceinline__ void gld16(const void* g, void* l) {
  __builtin_amdgcn_global_load_lds(
      (const __attribute__((address_space(1))) void*)g,
      (__attribute__((address_space(3))) void*)l, 16, 0, 0);
}

__device__ __forceinline__ uint32_t rotl32(uint32_t x, uint32_t d) {
  return (x << d) | (x >> (32u - d));
}

// threefry2x32-20, key=(0,42), partitionable, out = x0^x1  (verified R1/R4/R5)
__device__ __forceinline__ bool regrow(uint32_t b, uint32_t hts) {
  const uint32_t ks1 = 42u;
  const uint32_t ks2 = 0x1BD11BDAu ^ 42u;
  uint32_t x0 = 0u;
  uint32_t x1 = b * 0x4000000u + hts;
  x1 += ks1;
#define TF_R(r) { x0 += x1; x1 = rotl32(x1, r); x1 ^= x0; }
  TF_R(13) TF_R(15) TF_R(26) TF_R(6)  x0 += ks1; x1 += ks2 + 1u;
  TF_R(17) TF_R(29) TF_R(16) TF_R(24) x0 += ks2; x1 += 0u  + 2u;
  TF_R(13) TF_R(15) TF_R(26) TF_R(6)  x0 += 0u;  x1 += ks1 + 3u;
  TF_R(17) TF_R(29) TF_R(16) TF_R(24) x0 += ks1; x1 += ks2 + 4u;
  TF_R(13) TF_R(15) TF_R(26) TF_R(6)  x0 += ks2; x1 += 0u  + 5u;
#undef TF_R
  uint32_t r32 = x0 ^ x1;
  float f = __uint_as_float((r32 >> 9) | 0x3f800000u) - 1.0f;
  return f < 0.05f;
}

// ---------------------------------------------------------------------------
// conv_x: x [4096][1024] f32 -> xh/xl swizzled f16. 1 thread = 8 elems.
// ---------------------------------------------------------------------------
__global__ __launch_bounds__(256) void conv_x(const float* __restrict__ x,
                                              _Float16* __restrict__ xh,
                                              _Float16* __restrict__ xl) {
  int idx = blockIdx.x * 256 + threadIdx.x;
  int row = idx >> 7;
  int c8 = (idx & 127) << 3;
  const float* s = x + (size_t)row * 1024 + c8;
  float4 v0 = *(const float4*)s;
  float4 v1 = *(const float4*)(s + 4);
  float vv[8] = {v0.x, v0.y, v0.z, v0.w, v1.x, v1.y, v1.z, v1.w};
  half8 hh, ll;
#pragma unroll
  for (int i = 0; i < 8; ++i) {
    hh[i] = (_Float16)vv[i];
    ll[i] = (_Float16)(vv[i] - (float)hh[i]);
  }
  size_t o = (size_t)row * 1024 + (c8 ^ ((row & 7) << 3));
  *(half8*)&xh[o] = hh;
  *(half8*)&xl[o] = ll;
}

// ---------------------------------------------------------------------------
// conv_w: W [1024][N] f32 -> Wth/Wtl [N][1024] f16 transposed + swizzled.
// ---------------------------------------------------------------------------
__global__ __launch_bounds__(256) void conv_w(const float* __restrict__ W, int N,
                                              _Float16* __restrict__ Wth,
                                              _Float16* __restrict__ Wtl) {
  __shared__ float sW[64][68];
  const int n0 = blockIdx.x * 64, k0 = blockIdx.y * 64;
  const int t = threadIdx.x;
  const int kr = t >> 2, nc = (t & 3) * 16;
#pragma unroll
  for (int j = 0; j < 4; ++j)
    *(float4*)&sW[kr][nc + 4 * j] =
        *(const float4*)&W[(size_t)(k0 + kr) * N + n0 + nc + 4 * j];
  __syncthreads();
  const int nl = t >> 2, ks = (t & 3) * 16;
#pragma unroll
  for (int j = 0; j < 2; ++j) {
    int k8 = ks + j * 8;
    half8 hh, ll;
#pragma unroll
    for (int e = 0; e < 8; ++e) {
      float v = sW[k8 + e][nl];
      hh[e] = (_Float16)v;
      ll[e] = (_Float16)(v - (float)hh[e]);
    }
    size_t o = (size_t)(n0 + nl) * 1024 + ((k0 + k8) ^ (((n0 + nl) & 7) << 3));
    *(half8*)&Wth[o] = hh;
    *(half8*)&Wtl[o] = ll;
  }
}

// ---------------------------------------------------------------------------
// f16x3 GEMM (unchanged from R5, validated).
// ---------------------------------------------------------------------------
template <int PRE>
__global__ __launch_bounds__(256) void gemm_f16x3(
    const _Float16* __restrict__ Ah, const _Float16* __restrict__ Al,
    const float* __restrict__ Afp,
    const _Float16* __restrict__ Bth, const _Float16* __restrict__ Btl,
    const float* __restrict__ bias, int N, int outMode,
    _Float16* __restrict__ Qh, _Float16* __restrict__ Ql,
    _Float16* __restrict__ Kh, _Float16* __restrict__ Kl,
    _Float16* __restrict__ Vt, float* __restrict__ out)
{
  __shared__ _Float16 sAh[8192], sAl[8192], sBh[8192], sBl[8192];
  const int tid = threadIdx.x;
  const int wv = tid >> 6, lane = tid & 63;
  const int lg = lane >> 4, m15 = lane & 15;
  const int wr = wv >> 1, wc = wv & 1;
  const int m0 = blockIdx.y << 7, n0 = blockIdx.x << 7;
  const int srow = lane >> 3;
  const int schk = (lane & 7) << 3;

  f32x4 acc[4][4];
#pragma unroll
  for (int i = 0; i < 4; ++i)
#pragma unroll
    for (int j = 0; j < 4; ++j) acc[i][j] = (f32x4){0.f, 0.f, 0.f, 0.f};

  for (int g = 0; g < 16; ++g) {
    __syncthreads();
#pragma unroll
    for (int i = 0; i < 4; ++i) {
      int rb = (wv << 5) + (i << 3);
      size_t so = (size_t)(n0 + rb + srow) * 1024 + (g << 6) + schk;
      gld16(Bth + so, &sBh[rb << 6]);
      gld16(Btl + so, &sBl[rb << 6]);
    }
    if (PRE) {
#pragma unroll
      for (int i = 0; i < 4; ++i) {
        int rb = (wv << 5) + (i << 3);
        size_t so = (size_t)(m0 + rb + srow) * 1024 + (g << 6) + schk;
        gld16(Ah + so, &sAh[rb << 6]);
        gld16(Al + so, &sAl[rb << 6]);
      }
    } else {
      int r = tid >> 1, c0 = (tid & 1) << 5;
      const float* src = Afp + (size_t)(m0 + r) * 1024 + (g << 6) + c0;
#pragma unroll
      for (int i = 0; i < 8; ++i) {
        float4 v = *(const float4*)(src + (i << 2));
        half4 hh = {(_Float16)v.x, (_Float16)v.y, (_Float16)v.z, (_Float16)v.w};
        half4 ll = {(_Float16)(v.x - (float)hh[0]), (_Float16)(v.y - (float)hh[1]),
                    (_Float16)(v.z - (float)hh[2]), (_Float16)(v.w - (float)hh[3])};
        int off = (r << 6) + ((c0 + (i << 2)) ^ ((r & 7) << 3));
        *(half4*)&sAh[off] = hh;
        *(half4*)&sAl[off] = ll;
      }
    }
    __syncthreads();

#pragma unroll
    for (int ks = 0; ks < 2; ++ks) {
      half8 ah[4], al[4], bh[4], bl[4];
#pragma unroll
      for (int mi = 0; mi < 4; ++mi) {
        int row = (wr << 6) + (mi << 4) + m15;
        int off = (row << 6) + (((ks << 5) + (lg << 3)) ^ ((row & 7) << 3));
        ah[mi] = *(const half8*)&sAh[off];
        al[mi] = *(const half8*)&sAl[off];
      }
#pragma unroll
      for (int nj = 0; nj < 4; ++nj) {
        int row = (wc << 6) + (nj << 4) + m15;
        int off = (row << 6) + (((ks << 5) + (lg << 3)) ^ ((row & 7) << 3));
        bh[nj] = *(const half8*)&sBh[off];
        bl[nj] = *(const half8*)&sBl[off];
      }
#pragma unroll
      for (int mi = 0; mi < 4; ++mi)
#pragma unroll
        for (int nj = 0; nj < 4; ++nj) {
          acc[mi][nj] = MFMA16(ah[mi], bh[nj], acc[mi][nj]);
          acc[mi][nj] = MFMA16(ah[mi], bl[nj], acc[mi][nj]);
          acc[mi][nj] = MFMA16(al[mi], bh[nj], acc[mi][nj]);
        }
    }
  }

#pragma unroll
  for (int nj = 0; nj < 4; ++nj) {
    int n = n0 + (wc << 6) + (nj << 4) + m15;
    float bv = bias[n];
    int which = n >> 10;
    int hh_ = (n & 1023) >> 6;
    int d = n & 63;
#pragma unroll
    for (int mi = 0; mi < 4; ++mi) {
#pragma unroll
      for (int r = 0; r < 4; ++r) {
        int m = m0 + (wr << 6) + (mi << 4) + (lg << 2) + r;
        float v = acc[mi][nj][r] + bv;
        if (outMode == 1) {
          out[(size_t)m * N + n] = v;
        } else {
          _Float16 hi = (_Float16)v;
          _Float16 lo = (_Float16)(v - (float)hi);
          int b = m >> 11, t = m & 2047;
          if (which == 2) {
            size_t o = ((size_t)((b << 4) + hh_) * 64 + d) * 2048
                     + (t ^ ((d & 7) << 3));
            Vt[o] = hi;
          } else {
            size_t o = ((size_t)((b << 4) + hh_) * 2048 + t) * 64
                     + (d ^ ((t & 7) << 3));
            if (which == 0) { Qh[o] = hi; Ql[o] = lo; }
            else            { Kh[o] = hi; Kl[o] = lo; }
          }
        }
      }
    }
  }
}

// ---------------------------------------------------------------------------
// MFMA attention, R5 shape (4 waves, 64-row q-tile, {p,31-p} pairing) +
// double-buffered K/V staging with counted vmcnt. LDS 72KB -> 2 blocks/CU.
// ---------------------------------------------------------------------------
__global__ __launch_bounds__(256) void attn_mfma(
    const _Float16* __restrict__ Qhg, const _Float16* __restrict__ Qlg,
    const _Float16* __restrict__ Khg, const _Float16* __restrict__ Klg,
    const _Float16* __restrict__ Vtg,
    _Float16* __restrict__ AOh, _Float16* __restrict__ AOl)
{
  __shared__ _Float16 sQh[4096], sQl[4096];
  __shared__ _Float16 sKh[2][4096], sKl[2][4096];
  __shared__ _Float16 sVt[2][4096];
  __shared__ _Float16 sP[4096];

  const int tid = threadIdx.x;
  const int wv = tid >> 6, lane = tid & 63;
  const int lg = lane >> 4, m15 = lane & 15;
  const int h = blockIdx.y, b = blockIdx.z;
  const size_t bh = (size_t)(b * 16 + h);
  const _Float16* Qhb = Qhg + bh * 2048 * 64;
  const _Float16* Qlb = Qlg + bh * 2048 * 64;
  const _Float16* Khb = Khg + bh * 2048 * 64;
  const _Float16* Klb = Klg + bh * 2048 * 64;
  const _Float16* Vtb = Vtg + bh * 64 * 2048;

  const int srow = lane >> 3, schk = (lane & 7) << 3;
  const int w16 = wv << 4;

  for (int hv = 0; hv < 2; ++hv) {
    const int qt = hv ? (31 - (int)blockIdx.x) : (int)blockIdx.x;
    const int t0 = qt << 6;

    __syncthreads();
    {
      size_t o0 = (size_t)(t0 + w16 + srow) * 64 + schk;
      size_t o1 = (size_t)(t0 + w16 + 8 + srow) * 64 + schk;
      gld16(Qhb + o0, &sQh[w16 << 6]);
      gld16(Qhb + o1, &sQh[(w16 + 8) << 6]);
      gld16(Qlb + o0, &sQl[w16 << 6]);
      gld16(Qlb + o1, &sQl[(w16 + 8) << 6]);
    }
    __syncthreads();

    const int qrow = w16 + m15;
    const int qsw = (qrow & 7) << 3;
    const half8 qh0 = *(const half8*)&sQh[(qrow << 6) + ((lg << 3) ^ qsw)];
    const half8 qh1 = *(const half8*)&sQh[(qrow << 6) + (((lg << 3) + 32) ^ qsw)];
    const half8 ql0 = *(const half8*)&sQl[(qrow << 6) + ((lg << 3) ^ qsw)];
    const half8 ql1 = *(const half8*)&sQl[(qrow << 6) + (((lg << 3) + 32) ^ qsw)];

    float m_[4], l_[4];
#pragma unroll
    for (int r = 0; r < 4; ++r) { m_[r] = -INFINITY; l_[r] = 0.0f; }

    // ---- pass 1 prologue: stage K tile 0 into buf 0 (4 gld16/wave) ----
    {
      size_t o0 = (size_t)(w16 + srow) * 64 + schk;
      size_t o1 = (size_t)(w16 + 8 + srow) * 64 + schk;
      gld16(Khb + o0, &sKh[0][w16 << 6]);
      gld16(Khb + o1, &sKh[0][(w16 + 8) << 6]);
      gld16(Klb + o0, &sKl[0][w16 << 6]);
      gld16(Klb + o1, &sKl[0][(w16 + 8) << 6]);
    }

    // ---------------- pass 1: online m, l ----------------
    for (int kt = 0; kt <= qt; ++kt) {
      const int cur = kt & 1;
      SBAR();        // b1: closes prev iter's reads of buf cur^1
      SCHED0();
      if (kt < qt) {
        size_t o0 = (size_t)(((kt + 1) << 6) + w16 + srow) * 64 + schk;
        size_t o1 = (size_t)(((kt + 1) << 6) + w16 + 8 + srow) * 64 + schk;
        gld16(Khb + o0, &sKh[cur ^ 1][w16 << 6]);
        gld16(Khb + o1, &sKh[cur ^ 1][(w16 + 8) << 6]);
        gld16(Klb + o0, &sKl[cur ^ 1][w16 << 6]);
        gld16(Klb + o1, &sKl[cur ^ 1][(w16 + 8) << 6]);
        asm volatile("s_waitcnt vmcnt(4)" ::: "memory");
      } else {
        asm volatile("s_waitcnt vmcnt(0)" ::: "memory");
      }
      SCHED0();
      SBAR();        // b2: all waves' cur loads done
      SCHED0();

      float sc[4][4];
#pragma unroll
      for (int nt = 0; nt < 4; ++nt) {
        const int krow = (nt << 4) + m15;
        const int ksw = (krow & 7) << 3;
        half8 kh0 = *(const half8*)&sKh[cur][(krow << 6) + ((lg << 3) ^ ksw)];
        half8 kh1 = *(const half8*)&sKh[cur][(krow << 6) + (((lg << 3) + 32) ^ ksw)];
        half8 kl0 = *(const half8*)&sKl[cur][(krow << 6) + ((lg << 3) ^ ksw)];
        half8 kl1 = *(const half8*)&sKl[cur][(krow << 6) + (((lg << 3) + 32) ^ ksw)];
        f32x4 c = {0.f, 0.f, 0.f, 0.f};
        c = MFMA16(qh0, kh0, c);
        c = MFMA16(qh1, kh1, c);
        c = MFMA16(qh0, kl0, c);
        c = MFMA16(qh1, kl1, c);
        c = MFMA16(ql0, kh0, c);
        c = MFMA16(ql1, kh1, c);
#pragma unroll
        for (int r = 0; r < 4; ++r) {
          float s = c[r] * 0.125f;
          if (kt == qt && ((nt << 4) + m15) > (w16 + (lg << 2) + r)) s = -1e30f;
          sc[nt][r] = s;
        }
      }
#pragma unroll
      for (int r = 0; r < 4; ++r) {
        float tm = fmaxf(fmaxf(sc[0][r], sc[1][r]), fmaxf(sc[2][r], sc[3][r]));
        tm = fmaxf(tm, __shfl_xor(tm, 1));
        tm = fmaxf(tm, __shfl_xor(tm, 2));
        tm = fmaxf(tm, __shfl_xor(tm, 4));
        tm = fmaxf(tm, __shfl_xor(tm, 8));
        float mn = fmaxf(m_[r], tm);
        float ps = __expf(sc[0][r] - mn) + __expf(sc[1][r] - mn)
                 + __expf(sc[2][r] - mn) + __expf(sc[3][r] - mn);
        ps += __shfl_xor(ps, 1);
        ps += __shfl_xor(ps, 2);
        ps += __shfl_xor(ps, 4);
        ps += __shfl_xor(ps, 8);
        l_[r] = l_[r] * __expf(m_[r] - mn) + ps;
        m_[r] = mn;
      }
    }

    float rl[4];
#pragma unroll
    for (int r = 0; r < 4; ++r) rl[r] = 1.0f / l_[r];

    f32x4 oacc[4];
#pragma unroll
    for (int nt = 0; nt < 4; ++nt) oacc[nt] = (f32x4){0.f, 0.f, 0.f, 0.f};

    const uint32_t hqbase = (uint32_t)(h * 2048 + t0 + w16 + (lg << 2)) * 2048u;

    // ---- pass 2 prologue ----
    SBAR();          // close pass-1 final reads before overwriting buf 0
    SCHED0();
    {
      size_t o0 = (size_t)(w16 + srow) * 64 + schk;
      size_t o1 = (size_t)(w16 + 8 + srow) * 64 + schk;
      gld16(Khb + o0, &sKh[0][w16 << 6]);
      gld16(Khb + o1, &sKh[0][(w16 + 8) << 6]);
      gld16(Klb + o0, &sKl[0][w16 << 6]);
      gld16(Klb + o1, &sKl[0][(w16 + 8) << 6]);
      size_t v0 = (size_t)(w16 + srow) * 2048 + schk;
      size_t v1 = (size_t)(w16 + 8 + srow) * 2048 + schk;
      gld16(Vtb + v0, &sVt[0][w16 << 6]);
      gld16(Vtb + v1, &sVt[0][(w16 + 8) << 6]);
    }

    // ---------------- pass 2: p -> prune/regrow -> PV ----------------
    for (int kt = 0; kt <= qt; ++kt) {
      const int cur = kt & 1;
      SBAR();        // b1: closes prev iter's PV reads of buf cur^1 / sP
      SCHED0();
      if (kt < qt) {
        size_t o0 = (size_t)(((kt + 1) << 6) + w16 + srow) * 64 + schk;
        size_t o1 = (size_t)(((kt + 1) << 6) + w16 + 8 + srow) * 64 + schk;
        gld16(Khb + o0, &sKh[cur ^ 1][w16 << 6]);
        gld16(Khb + o1, &sKh[cur ^ 1][(w16 + 8) << 6]);
        gld16(Klb + o0, &sKl[cur ^ 1][w16 << 6]);
        gld16(Klb + o1, &sKl[cur ^ 1][(w16 + 8) << 6]);
        size_t v0 = (size_t)(w16 + srow) * 2048 + ((kt + 1) << 6) + schk;
        size_t v1 = (size_t)(w16 + 8 + srow) * 2048 + ((kt + 1) << 6) + schk;
        gld16(Vtb + v0, &sVt[cur ^ 1][w16 << 6]);
        gld16(Vtb + v1, &sVt[cur ^ 1][(w16 + 8) << 6]);
        asm volatile("s_waitcnt vmcnt(6)" ::: "memory");
      } else {
        asm volatile("s_waitcnt vmcnt(0)" ::: "memory");
      }
      SCHED0();
      SBAR();        // b2: all waves' cur loads done
      SCHED0();

      float sc[4][4];
#pragma unroll
      for (int nt = 0; nt < 4; ++nt) {
        const int krow = (nt << 4) + m15;
        const int ksw = (krow & 7) << 3;
        half8 kh0 = *(const half8*)&sKh[cur][(krow << 6) + ((lg << 3) ^ ksw)];
        half8 kh1 = *(const half8*)&sKh[cur][(krow << 6) + (((lg << 3) + 32) ^ ksw)];
        half8 kl0 = *(const half8*)&sKl[cur][(krow << 6) + ((lg << 3) ^ ksw)];
        half8 kl1 = *(const half8*)&sKl[cur][(krow << 6) + (((lg << 3) + 32) ^ ksw)];
        f32x4 c = {0.f, 0.f, 0.f, 0.f};
        c = MFMA16(qh0, kh0, c);
        c = MFMA16(qh1, kh1, c);
        c = MFMA16(qh0, kl0, c);
        c = MFMA16(qh1, kl1, c);
        c = MFMA16(ql0, kh0, c);
        c = MFMA16(ql1, kh1, c);
#pragma unroll
        for (int r = 0; r < 4; ++r) {
          float s = c[r] * 0.125f;
          if (kt == qt && ((nt << 4) + m15) > (w16 + (lg << 2) + r)) s = -1e30f;
          sc[nt][r] = s;
        }
      }

#pragma unroll
      for (int nt = 0; nt < 4; ++nt) {
#pragma unroll
        for (int r = 0; r < 4; ++r) {
          float pv = __expf(sc[nt][r] - m_[r]) * rl[r];
          float outp = 0.0f;
          if (pv > 0.01f) {
            outp = pv;
          } else if (pv > 0.0f) {
            uint32_t hts = hqbase + (uint32_t)r * 2048u
                         + (uint32_t)((kt << 6) + (nt << 4) + m15);
            if (regrow((uint32_t)b, hts)) outp = pv;
          }
          int q = w16 + (lg << 2) + r;
          sP[(q << 6) + (((nt << 4) + m15) ^ ((q & 7) << 3))] = (_Float16)outp;
        }
      }
      asm volatile("s_waitcnt lgkmcnt(0)" ::: "memory");
      SCHED0();
      SBAR();        // b3: sP visible (no vmem drain; next-tile loads stay live)
      SCHED0();

      const int prow = w16 + m15;
      const int psw = (prow & 7) << 3;
      half8 pa0 = *(const half8*)&sP[(prow << 6) + ((lg << 3) ^ psw)];
      half8 pa1 = *(const half8*)&sP[(prow << 6) + (((lg << 3) + 32) ^ psw)];
#pragma unroll
      for (int nt = 0; nt < 4; ++nt) {
        const int vrow = (nt << 4) + m15;
        const int vsw = (vrow & 7) << 3;
        half8 vb0 = *(const half8*)&sVt[cur][(vrow << 6) + ((lg << 3) ^ vsw)];
        half8 vb1 = *(const half8*)&sVt[cur][(vrow << 6) + (((lg << 3) + 32) ^ vsw)];
        oacc[nt] = MFMA16(pa0, vb0, oacc[nt]);
        oacc[nt] = MFMA16(pa1, vb1, oacc[nt]);
      }
    }

    // epilogue: AOh/AOl [4096][1024] swizzled by (row&7)
#pragma unroll
    for (int nt = 0; nt < 4; ++nt)
#pragma unroll
      for (int r = 0; r < 4; ++r) {
        int q = t0 + w16 + (lg << 2) + r;
        int col = (h << 6) + (nt << 4) + m15;
        int mrow = (b << 11) + q;
        float v = oacc[nt][r];
        _Float16 hi = (_Float16)v;
        _Float16 lo = (_Float16)(v - (float)hi);
        size_t o = (size_t)mrow * 1024 + (col ^ ((mrow & 7) << 3));
        AOh[o] = hi;
        AOl[o] = lo;
      }
  }
}

// ---------------------------------------------------------------------------
extern "C" void kernel_launch(void* const* d_in, const int* in_sizes, int n_in,
                              void* d_out, int out_size, void* d_ws, size_t ws_size,
                              hipStream_t stream) {
  const float* x    = (const float*)d_in[0];
  const float* Wqkv = (const float*)d_in[1];
  const float* bqkv = (const float*)d_in[2];
  const float* Wout = (const float*)d_in[3];
  const float* bout = (const float*)d_in[4];
  float* out = (float*)d_out;

  const size_t MB = 1u << 20;
  char* w = (char*)d_ws;
  _Float16* Qh = (_Float16*)(w);
  _Float16* Ql = (_Float16*)(w + 8 * MB);
  _Float16* Kh = (_Float16*)(w + 16 * MB);
  _Float16* Kl = (_Float16*)(w + 24 * MB);
  _Float16* Vt = (_Float16*)(w + 32 * MB);

  const bool pre = (ws_size >= 72 * MB);
  _Float16 *xh, *xl, *Wqh, *Wql, *Woh, *Wol, *AOh, *AOl;
  if (pre) {
    xh  = (_Float16*)(w + 40 * MB);
    xl  = (_Float16*)(w + 48 * MB);
    Wqh = (_Float16*)(w + 56 * MB);
    Wql = (_Float16*)(w + 62 * MB);
    Woh = (_Float16*)(w + 68 * MB);
    Wol = (_Float16*)(w + 70 * MB);
  } else {
    xh = xl = nullptr;
    Wqh = (_Float16*)(w + 40 * MB);
    Wql = (_Float16*)(w + 46 * MB);
    Woh = (_Float16*)(w + 56 * MB);
    Wol = (_Float16*)(w + 58 * MB);
  }
  AOh = (_Float16*)(w + 40 * MB);
  AOl = (_Float16*)(w + 48 * MB);

  dim3 blk(256);
  if (pre) conv_x<<<2048, blk, 0, stream>>>(x, xh, xl);
  conv_w<<<dim3(48, 16), blk, 0, stream>>>(Wqkv, 3072, Wqh, Wql);
  conv_w<<<dim3(16, 16), blk, 0, stream>>>(Wout, 1024, Woh, Wol);

  if (pre)
    gemm_f16x3<1><<<dim3(24, 32), blk, 0, stream>>>(
        xh, xl, nullptr, Wqh, Wql, bqkv, 3072, 0, Qh, Ql, Kh, Kl, Vt, nullptr);
  else
    gemm_f16x3<0><<<dim3(24, 32), blk, 0, stream>>>(
        nullptr, nullptr, x, Wqh, Wql, bqkv, 3072, 0, Qh, Ql, Kh, Kl, Vt, nullptr);

  attn_mfma<<<dim3(16, 16, 2), blk, 0, stream>>>(Qh, Ql, Kh, Kl, Vt, AOh, AOl);

  gemm_f16x3<1><<<dim3(8, 32), blk, 0, stream>>>(
      AOh, AOl, nullptr, Woh, Wol, bout, 1024, 1,
      nullptr, nullptr, nullptr, nullptr, nullptr, out);
}